// Round 5
// baseline (189.150 us; speedup 1.0000x reference)
//
#include <hip/hip_runtime.h>

using i32x4 = __attribute__((ext_vector_type(4))) int;
using i32x16 = __attribute__((ext_vector_type(16))) int;

#define DEVI static __device__ __forceinline__

DEVI void gload_lds16(const void* g, void* l) {
  __builtin_amdgcn_global_load_lds(
      (const __attribute__((address_space(1))) void*)g,
      (__attribute__((address_space(3))) void*)l, 16, 0, 0);
}

template <int N> DEVI void vmcnt_n() {
  asm volatile("s_waitcnt vmcnt(%0)" ::"n"(N) : "memory");
}
template <int N> DEVI void lgkm_n() {
  asm volatile("s_waitcnt lgkmcnt(%0)" ::"n"(N) : "memory");
}

#define FENCE() asm volatile("" ::: "memory")
#define BARX()                    \
  do {                            \
    FENCE();                      \
    __builtin_amdgcn_s_barrier(); \
    FENCE();                      \
  } while (0)
#define SCHB() __builtin_amdgcn_sched_barrier(0)
#define PRIO1() __builtin_amdgcn_s_setprio(1)
#define PRIO0() __builtin_amdgcn_s_setprio(0)

// ---------------- pack int32 weights -> int8 ----------------
__global__ void __launch_bounds__(256) pack_w_kernel(const int* __restrict__ w,
                                                     signed char* __restrict__ o,
                                                     int n4) {
  int stride = gridDim.x * blockDim.x;
  for (int i = blockIdx.x * blockDim.x + threadIdx.x; i < n4; i += stride) {
    int4 v = reinterpret_cast<const int4*>(w)[i];
    char4 c;
    c.x = (signed char)v.x;
    c.y = (signed char)v.y;
    c.z = (signed char)v.z;
    c.w = (signed char)v.w;
    reinterpret_cast<char4*>(o)[i] = c;
  }
}

// ---------------- quantize fp32 x -> int8 ----------------
__global__ void __launch_bounds__(256) quant_x_kernel(const float* __restrict__ x,
                                                      signed char* __restrict__ o,
                                                      const float* __restrict__ amax,
                                                      int n4) {
  const float s = 127.0f / amax[0];
  int stride = gridDim.x * blockDim.x;
  for (int i = blockIdx.x * blockDim.x + threadIdx.x; i < n4; i += stride) {
    float4 v = reinterpret_cast<const float4*>(x)[i];
    char4 c;
    float q;
    q = fminf(fmaxf(rintf(__fmul_rn(v.x, s)), -127.0f), 127.0f); c.x = (signed char)(int)q;
    q = fminf(fmaxf(rintf(__fmul_rn(v.y, s)), -127.0f), 127.0f); c.y = (signed char)(int)q;
    q = fminf(fmaxf(rintf(__fmul_rn(v.z, s)), -127.0f), 127.0f); c.z = (signed char)(int)q;
    q = fminf(fmaxf(rintf(__fmul_rn(v.w, s)), -127.0f), 127.0f); c.w = (signed char)(int)q;
    reinterpret_cast<char4*>(o)[i] = c;
  }
}

// ---------------- int8 GEMM, 256xBN, 32x32x32 MFMA, 4-window schedule -----
// A: [M,K] i8 row-major; W: [N,K] i8 row-major. BK = 128 bytes.
// 8 waves (2M x 4N), per-wave C = 128 x (BN/4) = 4m x NW n-frags of 32x32.
// Double-buffered XOR-swizzled LDS; af ping-pong pipelined one window ahead;
// bf read once per tile at p0-front; counted vmcnt/lgkm; setprio on MFMA.

#define GB(b, j, k0_)                                           \
  gload_lds16(Wb + (size_t)((j)*64 + srow) * K + (k0_),         \
              &lds[b][ABYTES + (j)*8192 + tid * 16])
#define GA(b, r0, k0_)                                          \
  gload_lds16(Ab + (size_t)((r0) + srow) * K + (k0_),           \
              &lds[b][(r0)*128 + tid * 16])

#define STG_B_EARLY(b, kt)                                              \
  do {                                                                  \
    const int k0_ = (kt)*128 + scol;                                    \
    _Pragma("unroll") for (int j = 0; j < NBE; ++j) GB(b, j, k0_);      \
  } while (0)
#define STG_B_LATE(b, kt)                                               \
  do {                                                                  \
    const int k0_ = (kt)*128 + scol;                                    \
    _Pragma("unroll") for (int j = NBE; j < NN; ++j) GB(b, j, k0_);     \
  } while (0)
#define STG_A01(b, kt)               \
  do {                               \
    const int k0_ = (kt)*128 + scol; \
    GA(b, 0, k0_);                   \
    GA(b, 128, k0_);                 \
  } while (0)
#define STG_A23(b, kt)               \
  do {                               \
    const int k0_ = (kt)*128 + scol; \
    GA(b, 64, k0_);                  \
    GA(b, 192, k0_);                 \
  } while (0)

// 32x32x32 fragment reads: lane holds row=lane&31, k-bytes (2*kh+hv)*16
// (hv=lane>>5); slot XOR-swizzled by row&7 (= lane&7 since tiles are
// 32-row-aligned).
#define RD_AF32(dst, b, mi)                                                 \
  do {                                                                      \
    const int ab_ = (wrl + (mi)*32 + ro32) * 128;                           \
    dst[0] = *(const i32x4*)&lds[b][ab_ + sl0];                             \
    dst[1] = *(const i32x4*)&lds[b][ab_ + sl1];                             \
    dst[2] = *(const i32x4*)&lds[b][ab_ + sl2];                             \
    dst[3] = *(const i32x4*)&lds[b][ab_ + sl3];                             \
  } while (0)

#define READ_BF32(b)                                                        \
  do {                                                                      \
    _Pragma("unroll") for (int n = 0; n < NW; ++n) {                        \
      const int bb_ = ABYTES + (wcl + n * 32 + ro32) * 128;                 \
      bf[n][0] = *(const i32x4*)&lds[b][bb_ + sl0];                         \
      bf[n][1] = *(const i32x4*)&lds[b][bb_ + sl1];                         \
      bf[n][2] = *(const i32x4*)&lds[b][bb_ + sl2];                         \
      bf[n][3] = *(const i32x4*)&lds[b][bb_ + sl3];                         \
    }                                                                       \
  } while (0)

#define MFMA_W(mi, af)                                                      \
  do {                                                                      \
    _Pragma("unroll") for (int kh = 0; kh < 4; ++kh) {                      \
      _Pragma("unroll") for (int n = 0; n < NW; ++n) {                      \
        acc[mi][n] = __builtin_amdgcn_mfma_i32_32x32x32_i8(                 \
            af[kh], bf[n][kh], acc[mi][n], 0, 0, 0);                        \
      }                                                                     \
    }                                                                       \
  } while (0)

#define TILE_STEADY(b, t)                       \
  do {                                          \
    READ_BF32(b);                               \
    RD_AF32(afB, b, 1);                         \
    STG_B_LATE(1 - (b), (t) + 1);               \
    STG_A01(1 - (b), (t) + 1);                  \
    vmcnt_n<NN + 2>();                          \
    BARX(); lgkm_n<4>(); SCHB();                \
    PRIO1(); MFMA_W(0, afA); PRIO0();           \
    RD_AF32(afA, b, 2);                         \
    STG_A23(1 - (b), (t) + 1);                  \
    BARX(); lgkm_n<4>(); SCHB();                \
    PRIO1(); MFMA_W(1, afB); PRIO0();           \
    RD_AF32(afB, b, 3);                         \
    vmcnt_n<2>();                               \
    BARX(); lgkm_n<4>(); SCHB();                \
    PRIO1(); MFMA_W(2, afA); PRIO0();           \
    RD_AF32(afA, 1 - (b), 0);                   \
    if ((t) + 2 < nt) STG_B_EARLY(b, (t) + 2);  \
    BARX(); lgkm_n<4>(); SCHB();                \
    PRIO1(); MFMA_W(3, afB); PRIO0();           \
  } while (0)

#define TILE_LAST(b)                            \
  do {                                          \
    READ_BF32(b);                               \
    RD_AF32(afB, b, 1);                         \
    vmcnt_n<0>();                               \
    BARX(); lgkm_n<4>(); SCHB();                \
    PRIO1(); MFMA_W(0, afA); PRIO0();           \
    RD_AF32(afA, b, 2);                         \
    BARX(); lgkm_n<4>(); SCHB();                \
    PRIO1(); MFMA_W(1, afB); PRIO0();           \
    RD_AF32(afB, b, 3);                         \
    BARX(); lgkm_n<4>(); SCHB();                \
    PRIO1(); MFMA_W(2, afA); PRIO0();           \
    BARX(); lgkm_n<0>(); SCHB();                \
    PRIO1(); MFMA_W(3, afB); PRIO0();           \
  } while (0)

template <int BN, int OUT_I8>
__global__ __launch_bounds__(512, 2) void gemm32_kernel(
    const signed char* __restrict__ A, const signed char* __restrict__ W,
    const int* __restrict__ bias, void* __restrict__ out, int M, int N, int K,
    const float* __restrict__ p_ain, const float* __restrict__ p_aw,
    const float* __restrict__ p_ab, const float* __restrict__ p_anext) {
  static_assert(BN == 256 || BN == 128, "");
  constexpr int NN = BN / 64;        // B staging chunks (64 rows each)
  constexpr int NBE = NN / 2;        // B loads issued one tile early (p3)
  constexpr int NW = BN / 128;       // 32-wide n-frags per wave
  constexpr int ABYTES = 256 * 128;  // 32 KiB A-tile
  __shared__ signed char lds[2][ABYTES + BN * 128];

  const int tid = threadIdx.x;
  const int lane = tid & 63;
  const int wave = tid >> 6;
  const int wrl = (wave >> 2) * 128;      // wave row offset in 256
  const int wcl = (wave & 3) * (BN / 4);  // wave col offset in BN
  const int tileM = blockIdx.y * 256;
  const int tileN = blockIdx.x * BN;

  const signed char* Ab = A + (size_t)tileM * K;
  const signed char* Wb = W + (size_t)tileN * K;

  const int srow = tid >> 3;                       // staging row 0..63
  const int scol = ((tid & 7) ^ (srow & 7)) * 16;  // inverse-swizzled src col

  const int ro32 = lane & 31;  // fragment row within 32
  const int hv = lane >> 5;    // k-half select within 32B chunk
  const int lx = lane & 7;     // swizzle key (== row&7 for 32-aligned tiles)
  const int sl0 = ((0 * 2 + hv) ^ lx) << 4;
  const int sl1 = ((1 * 2 + hv) ^ lx) << 4;
  const int sl2 = ((2 * 2 + hv) ^ lx) << 4;
  const int sl3 = ((3 * 2 + hv) ^ lx) << 4;

  const int nt = K >> 7;  // K-tiles of 128 bytes

  i32x16 acc[4][NW] = {};
  i32x4 afA[4], afB[4], bf[NW][4];

  // prologue: stage all of tile 0, then the early-B of tile 1
  {
    const int k0_ = scol;
#pragma unroll
    for (int j = 0; j < NN; ++j) GB(0, j, k0_);
    GA(0, 0, k0_);
    GA(0, 128, k0_);
    GA(0, 64, k0_);
    GA(0, 192, k0_);
  }
  FENCE();
  STG_B_EARLY(1, 1);
  vmcnt_n<NBE>();  // retire every tile-0 load; leave early-B(1) in flight
  BARX();
  RD_AF32(afA, 0, 0);

  for (int t = 0; t < nt - 2; t += 2) {
    TILE_STEADY(0, t);
    TILE_STEADY(1, t + 1);
  }
  TILE_STEADY(0, nt - 2);
  TILE_LAST(1);

  // ---- epilogue: dequant + bias (+ relu + requant) ----
  const float s1 = __fmul_rn(p_aw[0], p_ain[0]) / 16129.0f;  // a_w*a_in/127^2
  const float s2 = p_ab[0] / 127.0f;                         // a_b/127
  float qs = 0.0f;
  if (OUT_I8) qs = 127.0f / p_anext[0];

#pragma unroll
  for (int mi = 0; mi < 4; ++mi) {
#pragma unroll
    for (int n = 0; n < NW; ++n) {
      const int col = tileN + wcl + n * 32 + ro32;
      const float bv = __fmul_rn((float)bias[col], s2);
#pragma unroll
      for (int r = 0; r < 16; ++r) {
        const int row = tileM + wrl + mi * 32 + (r & 3) + 8 * (r >> 2) + 4 * hv;
        float y = __fadd_rn(__fmul_rn((float)acc[mi][n][r], s1), bv);
        if (OUT_I8) {
          float rl = fmaxf(y, 0.0f);
          float q = fminf(rintf(__fmul_rn(rl, qs)), 127.0f);
          ((signed char*)out)[(size_t)row * N + col] = (signed char)(int)q;
        } else {
          ((float*)out)[(size_t)row * N + col] = y;
        }
      }
    }
  }
}

extern "C" void kernel_launch(void* const* d_in, const int* in_sizes, int n_in,
                              void* d_out, int out_size, void* d_ws, size_t ws_size,
                              hipStream_t stream) {
  const float* x = (const float*)d_in[0];
  const int* W0 = (const int*)d_in[1];
  const int* b0 = (const int*)d_in[2];
  const int* W2 = (const int*)d_in[3];
  const int* b2 = (const int*)d_in[4];
  const int* W4 = (const int*)d_in[5];
  const int* b4 = (const int*)d_in[6];
  const float* a0_in = (const float*)d_in[7];
  const float* a0_w = (const float*)d_in[8];
  const float* a0_b = (const float*)d_in[9];
  const float* a2_in = (const float*)d_in[10];
  const float* a2_w = (const float*)d_in[11];
  const float* a2_b = (const float*)d_in[12];
  const float* a4_in = (const float*)d_in[13];
  const float* a4_w = (const float*)d_in[14];
  const float* a4_b = (const float*)d_in[15];

  constexpr int Bb = 4096, DIN = 2048, H = 4096, DOUT = 2048;
  constexpr size_t MB = 1u << 20;

  char* ws = (char*)d_ws;
  signed char* xq0 = (signed char*)(ws);           //  8 MB  [0,8)
  signed char* xq2 = (signed char*)(ws);           // 16 MB  [0,16) (aliases xq0+W0q, dead then)
  signed char* W0q = (signed char*)(ws + 8 * MB);  //  8 MB  [8,16)
  signed char* W2q = (signed char*)(ws + 16 * MB); // 16 MB  [16,32)
  signed char* W4q = (signed char*)(ws + 32 * MB); //  8 MB  [32,40)
  signed char* xq1 = (signed char*)(ws + 40 * MB); // 16 MB  [40,56)

  pack_w_kernel<<<2048, 256, 0, stream>>>(W0, W0q, H * DIN / 4);
  pack_w_kernel<<<2048, 256, 0, stream>>>(W2, W2q, H * H / 4);
  pack_w_kernel<<<2048, 256, 0, stream>>>(W4, W4q, DOUT * H / 4);
  quant_x_kernel<<<2048, 256, 0, stream>>>(x, xq0, a0_in, Bb * DIN / 4);

  gemm32_kernel<256, 1><<<dim3(H / 256, Bb / 256), 512, 0, stream>>>(
      xq0, W0q, b0, xq1, Bb, H, DIN, a0_in, a0_w, a0_b, a2_in);
  gemm32_kernel<256, 1><<<dim3(H / 256, Bb / 256), 512, 0, stream>>>(
      xq1, W2q, b2, xq2, Bb, H, H, a2_in, a2_w, a2_b, a4_in);
  gemm32_kernel<128, 0><<<dim3(DOUT / 128, Bb / 256), 512, 0, stream>>>(
      xq2, W4q, b4, d_out, Bb, DOUT, H, a4_in, a4_w, a4_b, a4_in);
}